// Round 10
// baseline (8996.676 us; speedup 1.0000x reference)
//
#include <hip/hip_runtime.h>

// LSTMFromEmbeddings: B=128, T=1024, E=256, H=256, C=2, bidirectional + meanpool + linear.
//
// R10 (= R9 with the DPP ctrl as a template constant, fixing the compile error):
//  rec: 32 persistent wgs = 16 groups (2 dir x 8 batch-blocks of 16) x 2 members
//       (128 units each). Weights in registers. Gate-quad col mapping -> gates are
//       transposed IN-WAVE via DPP quad_perm (no gates-LDS round trip, no B1 LDS
//       traffic). Each lane owns 4 (batch,unit-quad) gates -> publishes 2 tagged
//       words + writes own HS slice; polls ONE peer. lgkm-only barriers (2/step).
//  prep: bf16(x*mask) image in LDS-tile layout (gload_lds staging, 2 steps ahead).
//  head: out = (hsum/1024) @ W_lin^T + b_lin.

#define B_ 128
#define T_ 1024
#define E_ 256
#define H_ 256

typedef short short8 __attribute__((ext_vector_type(8)));
typedef float f32x4 __attribute__((ext_vector_type(4)));

__device__ __forceinline__ unsigned short f2bf(float f) {
  unsigned u = __builtin_bit_cast(unsigned, f);
  u += 0x7fffu + ((u >> 16) & 1u);  // RNE
  return (unsigned short)(u >> 16);
}
__device__ __forceinline__ f32x4 mfma16(short8 a, short8 b, f32x4 c) {
  return __builtin_amdgcn_mfma_f32_16x16x32_bf16(a, b, c, 0, 0, 0);
}
__device__ __forceinline__ float rcpf(float x) { return __builtin_amdgcn_rcpf(x); }

// proven R8 elementwise: 5 exp + 3 rcp per unit
__device__ __forceinline__ float lstm_ew(float gi, float gf, float gg, float go, float& c) {
  float ei = __expf(-gi), ef = __expf(-gf), eg = __expf(-2.f * gg);
  float di = 1.f + ei, df = 1.f + ef, dg = 1.f + eg;
  float r1 = rcpf(di * dg);
  float si = r1 * dg;
  float tg = 2.f * (r1 * di) - 1.f;
  c = rcpf(df) * c + si * tg;
  float eo = __expf(-go), ec = __expf(2.f * c);
  float do_ = 1.f + eo, dc = 1.f + ec;
  float r3 = rcpf(do_ * dc);
  float so = r3 * dc;
  float th = 1.f - 2.f * (r3 * do_);
  return so * th;
}

__device__ __forceinline__ short8 cvt8(f32x4 v0, f32x4 v1) {
  short8 o;
  o[0] = (short)f2bf(v0[0]); o[1] = (short)f2bf(v0[1]);
  o[2] = (short)f2bf(v0[2]); o[3] = (short)f2bf(v0[3]);
  o[4] = (short)f2bf(v1[0]); o[5] = (short)f2bf(v1[1]);
  o[6] = (short)f2bf(v1[2]); o[7] = (short)f2bf(v1[3]);
  return o;
}

__device__ __forceinline__ void bar_lds() {  // LDS-only barrier; vmem stays in flight
  asm volatile("s_waitcnt lgkmcnt(0)" ::: "memory");
  __builtin_amdgcn_s_barrier();
}

__device__ __forceinline__ void gload16(const void* g, void* l) {
  __builtin_amdgcn_global_load_lds(
      (const __attribute__((address_space(1))) void*)g,
      (__attribute__((address_space(3))) void*)l, 16, 0, 0);
}

template <int CTRL>
__device__ __forceinline__ float dppf(float v) {
  int x = __builtin_bit_cast(int, v);
  x = __builtin_amdgcn_update_dpp(0, x, CTRL, 0xF, 0xF, true);
  return __builtin_bit_cast(float, x);
}
#define DPP_X1 0xB1  // quad_perm [1,0,3,2]
#define DPP_X2 0x4E  // quad_perm [2,3,0,1]

// ---------------- prep: x image in LDS-tile layout ---------------------------
__global__ __launch_bounds__(256, 4) void prep_kernel(
    const float* __restrict__ x, const float* __restrict__ mask,
    unsigned short* __restrict__ img) {
  int gid = blockIdx.x * 256 + threadIdx.x;
  int i = gid & 511;
  int tt = (gid >> 9) & 1023;
  int bblk = gid >> 19;
  int r = i >> 5, s = i & 31, kc = s ^ (r & 7);
  int b = bblk * 16 + r;
  const f32x4* src = (const f32x4*)(x + ((size_t)b * T_ + tt) * E_ + kc * 8);
  float mk = mask[(size_t)b * T_ + tt];
  ((short8*)img)[gid] = cvt8(src[0] * mk, src[1] * mk);
}

// ---------------- rec: fused projection + recurrence --------------------------
// grid 32, 512 threads. g = bid & 15, m = bid >> 4 (members bid, bid+16: co-XCD
// heuristic). Member m owns units [m*128, m*128+128).
// Col mapping: col' = (4w+i)*16 + 4*qd + gate  ->  u_local = 16w + 4qd + i.
template <bool PREP>
__global__ __launch_bounds__(512, 1) void rec_kernel(
    const float* __restrict__ x, const float* __restrict__ mask,
    const unsigned short* __restrict__ img,
    const float* __restrict__ WihF, const float* __restrict__ WhhF,
    const float* __restrict__ bF, const float* __restrict__ WihB,
    const float* __restrict__ WhhB, const float* __restrict__ bB,
    unsigned long long* __restrict__ Hbuf, float* __restrict__ hsum) {
  __shared__ __align__(16) short XS[2][16 * 256];  // x stage, parity dbuf (16KB)
  __shared__ __align__(16) short HS[16 * 256];     // h stage (8KB)

  const int bid = blockIdx.x;
  const int g = bid & 15, m = bid >> 4;
  const int d = g >> 3, bblk = g & 7;
  const int tid = threadIdx.x;
  const int w = tid >> 6, l = tid & 63, l15 = l & 15, l4 = l >> 4;
  const int qd = l15 >> 2, qg = l15 & 3;
  const int sr = tid >> 5, sc = tid & 31;
  const int b_local = l4 * 4 + qg;        // post-transpose batch of this lane
  const int gb_s = bblk * 16 + sr;        // fallback staging batch

  const float* Wih = d ? WihB : WihF;
  const float* Whh = d ? WhhB : WhhF;
  const float* bias = d ? bB : bF;

  // ---- weight fragments -> registers (col mapping above) ----
  short8 wi[4][8], wh[4][8];
  float biasv[4];
#pragma unroll
  for (int i = 0; i < 4; ++i) {
    int ul = 16 * w + 4 * qd + i;
    size_t nat = (size_t)(qg * 256 + m * 128 + ul);
    biasv[i] = bias[nat];
#pragma unroll
    for (int kb = 0; kb < 8; ++kb) {
      const f32x4* pi = (const f32x4*)(Wih + nat * E_ + kb * 32 + l4 * 8);
      wi[i][kb] = cvt8(pi[0], pi[1]);
      const f32x4* ph = (const f32x4*)(Whh + nat * H_ + kb * 32 + l4 * 8);
      wh[i][kb] = cvt8(ph[0], ph[1]);
    }
  }

  // x image source pointer; one 8KB tile per t
  const int dstep = d ? -8192 : 8192;
  const char* gsrc = (const char*)img +
      ((size_t)(bblk * 1024 + (d ? (T_ - 1) : 0)) * 8192) + (size_t)tid * 16;

  // ---- prologue: HS=0; stage x_0 (and x_1 for PREP); acc = bias + xg_0 ----
  ((int4*)HS)[tid] = (int4){0, 0, 0, 0};
  if constexpr (PREP) {
    gload16(gsrc, (char*)XS[0] + w * 1024);
    gload16(gsrc + dstep, (char*)XS[1] + w * 1024);
    gsrc += 2 * dstep;
  } else {
    int ts = d ? (T_ - 1) : 0;
    const f32x4* px = (const f32x4*)(x + ((size_t)gb_s * T_ + ts) * E_ + sc * 8);
    float mk = mask[(size_t)gb_s * T_ + ts];
    ((short8*)XS[0])[sr * 32 + (sc ^ (sr & 7))] = cvt8(px[0] * mk, px[1] * mk);
  }
  __syncthreads();  // drains gloads + HS zeros visible

  f32x4 acc[4], accB[4];
#pragma unroll
  for (int i = 0; i < 4; ++i) {
    acc[i] = (f32x4){biasv[i], biasv[i], biasv[i], biasv[i]};
    accB[i] = (f32x4){0.f, 0.f, 0.f, 0.f};
  }
#pragma unroll
  for (int kp = 0; kp < 4; ++kp) {
    short8 a0 = ((short8*)XS[0])[l15 * 32 + ((kp * 8 + l4) ^ (l15 & 7))];
    short8 a1 = ((short8*)XS[0])[l15 * 32 + ((kp * 8 + 4 + l4) ^ (l15 & 7))];
#pragma unroll
    for (int i = 0; i < 4; ++i) {
      acc[i] = mfma16(a0, wi[i][2 * kp], acc[i]);
      accB[i] = mfma16(a1, wi[i][2 * kp + 1], accB[i]);
    }
  }
  __syncthreads();  // XS[0] consumed before first in-loop gload overwrites it

  const bool s1 = (l & 1) != 0;
  const bool s2 = (l & 2) != 0;
  float cs[4] = {0.f, 0.f, 0.f, 0.f};
  float hsums[4] = {0.f, 0.f, 0.f, 0.f};

  for (int t = 0; t < T_; ++t) {
    const bool more = (t + 1 < T_);

    if constexpr (PREP) {
      if (t + 2 < T_) {  // stage x_{t+2}; retired by this step's poll vmcnt + B2
        gload16(gsrc, (char*)XS[t & 1] + w * 1024);
        gsrc += dstep;
      }
    }
    f32x4 xv0, xv1;
    float mk = 0.f;
    if constexpr (!PREP) {
      if (more) {
        int ts = d ? (T_ - 2 - t) : (t + 1);
        const f32x4* px = (const f32x4*)(x + ((size_t)gb_s * T_ + ts) * E_ + sc * 8);
        xv0 = px[0]; xv1 = px[1];
        mk = mask[(size_t)gb_s * T_ + ts];
      }
    }

    // hh product into acc (acc holds bias + xg_t); HS holds h_t (zeros at t=0)
#pragma unroll
    for (int kp = 0; kp < 4; ++kp) {
      short8 a0 = ((short8*)HS)[l15 * 32 + ((kp * 8 + l4) ^ (l15 & 7))];
      short8 a1 = ((short8*)HS)[l15 * 32 + ((kp * 8 + 4 + l4) ^ (l15 & 7))];
#pragma unroll
      for (int i = 0; i < 4; ++i) {
        acc[i] = mfma16(a0, wh[i][2 * kp], acc[i]);
        accB[i] = mfma16(a1, wh[i][2 * kp + 1], accB[i]);
      }
    }
    bar_lds();  // B1: all waves done READING HS (h_{t+1} writes follow)

    // quad transpose (DPP) + ew: lane ends with gates (i,f,g,o) of
    // (b = 4*l4 + qg, u_local = 16w + 4qd + i), i = 0..3.
    float h[4];
#pragma unroll
    for (int i = 0; i < 4; ++i) {
      float a = acc[i][0] + accB[i][0];
      float b1 = acc[i][1] + accB[i][1];
      float c = acc[i][2] + accB[i][2];
      float dd = acc[i][3] + accB[i][3];
      float ap = dppf<DPP_X1>(a), bp = dppf<DPP_X1>(b1);
      float cp = dppf<DPP_X1>(c), dp = dppf<DPP_X1>(dd);
      float z0 = s1 ? bp : a, z1 = s1 ? b1 : ap;
      float z2 = s1 ? dp : c, z3 = s1 ? dd : cp;
      float z0p = dppf<DPP_X2>(z0), z1p = dppf<DPP_X2>(z1);
      float z2p = dppf<DPP_X2>(z2), z3p = dppf<DPP_X2>(z3);
      float t0 = s2 ? z2p : z0, t1 = s2 ? z3p : z1;
      float t2 = s2 ? z2 : z0p, t3 = s2 ? z3 : z1p;
      h[i] = lstm_ew(t0, t1, t2, t3, cs[i]);
      hsums[i] += h[i];
    }

    if (more) {
      const unsigned tag = (unsigned)(t + 1);
      const size_t base = ((size_t)g * 2 + (tag & 1)) * 16;

      // pack h pairs; publish 2 tagged words; write own HS slice directly
      unsigned pay0, pay1;
      asm("v_cvt_pk_bf16_f32 %0, %1, %2" : "=v"(pay0) : "v"(h[0]), "v"(h[1]));
      asm("v_cvt_pk_bf16_f32 %0, %1, %2" : "=v"(pay1) : "v"(h[2]), "v"(h[3]));
      size_t widx = (base + b_local) * 128 + m * 64 + 8 * w + 2 * qd;
      unsigned long long w0 = (((unsigned long long)tag) << 32) | pay0;
      unsigned long long w1 = (((unsigned long long)tag) << 32) | pay1;
      __hip_atomic_store(&Hbuf[widx], w0, __ATOMIC_RELAXED, __HIP_MEMORY_SCOPE_AGENT);
      __hip_atomic_store(&Hbuf[widx + 1], w1, __ATOMIC_RELAXED, __HIP_MEMORY_SCOPE_AGENT);
      asm volatile("" ::: "memory");  // publish before polls

      {  // own HS: 4 bf16 units at (b_local, global chunk m*16 + 2w + (qd>>1))
        int cg = m * 16 + 2 * w + (qd >> 1);
        int2 own = {(int)pay0, (int)pay1};
        *(int2*)((char*)HS +
                 (size_t)((b_local * 32 + (cg ^ (b_local & 7))) * 16 + 8 * (qd & 1))) = own;
      }

      if constexpr (!PREP) {
        ((short8*)XS[(t + 1) & 1])[sr * 32 + (sc ^ (sr & 7))] = cvt8(xv0 * mk, xv1 * mk);
        bar_lds();
      }

      // acc = bias + xg_{t+1} (fills publish->visibility window)
#pragma unroll
      for (int i = 0; i < 4; ++i) {
        acc[i] = (f32x4){biasv[i], biasv[i], biasv[i], biasv[i]};
        accB[i] = (f32x4){0.f, 0.f, 0.f, 0.f};
      }
      const short8* xsN = (const short8*)XS[(t + 1) & 1];
#pragma unroll
      for (int kp = 0; kp < 4; ++kp) {
        short8 a0 = xsN[l15 * 32 + ((kp * 8 + l4) ^ (l15 & 7))];
        short8 a1 = xsN[l15 * 32 + ((kp * 8 + 4 + l4) ^ (l15 & 7))];
#pragma unroll
        for (int i = 0; i < 4; ++i) {
          acc[i] = mfma16(a0, wi[i][2 * kp], acc[i]);
          accB[i] = mfma16(a1, wi[i][2 * kp + 1], accB[i]);
        }
      }

      // poll peer's words (half the lanes; every wave has pollers -> wave-wide
      // vmcnt covers this step's gloads too)
      int pc = sc >> 4;  // chunk's member
      if (pc != m) {
        const unsigned long long* rp = &Hbuf[(base + sr) * 128 + pc * 64 + (sc & 15) * 4];
        unsigned long long vv[4];
#pragma unroll
        for (int j = 0; j < 4; ++j)
          vv[j] = __hip_atomic_load(&rp[j], __ATOMIC_RELAXED, __HIP_MEMORY_SCOPE_AGENT);
        asm volatile("" ::: "memory");
        for (;;) {
          bool ok = true;
#pragma unroll
          for (int j = 0; j < 4; ++j) ok &= ((unsigned)(vv[j] >> 32) == tag);
          if (ok) break;
#pragma unroll
          for (int j = 0; j < 4; ++j)
            if ((unsigned)(vv[j] >> 32) != tag)
              vv[j] = __hip_atomic_load(&rp[j], __ATOMIC_RELAXED, __HIP_MEMORY_SCOPE_AGENT);
          asm volatile("" ::: "memory");
        }
        int4 hw;
        hw.x = (int)(unsigned)vv[0]; hw.y = (int)(unsigned)vv[1];
        hw.z = (int)(unsigned)vv[2]; hw.w = (int)(unsigned)vv[3];
        *(int4*)((char*)HS + (size_t)(sr * 32 + (sc ^ (sr & 7))) * 16) = hw;
      }
      bar_lds();  // B2: HS (own+peer) visible; XS fully read
    }
  }

  // pooled sums: lane owns (b = bblk*16 + b_local, units ub..ub+3), 16B store
  {
    int gb_t = bblk * 16 + b_local;
    int ub = m * 128 + 16 * w + 4 * qd;
    f32x4 hv = {hsums[0], hsums[1], hsums[2], hsums[3]};
    *(f32x4*)(hsum + ((size_t)d * B_ + gb_t) * H_ + ub) = hv;
  }
}

// ---------------- head: linear ----------------------------------------------
__global__ __launch_bounds__(256, 1) void head_kernel(
    const float* __restrict__ hsum, const float* __restrict__ Wlin,
    const float* __restrict__ blin, float* __restrict__ out) {
  int tid = threadIdx.x;  // 256 = 128 b x 2 c
  int b = tid >> 1, c = tid & 1;
  const f32x4* hf = (const f32x4*)(hsum + (size_t)b * H_);
  const f32x4* hbk = (const f32x4*)(hsum + (size_t)B_ * H_ + (size_t)b * H_);
  const f32x4* wl = (const f32x4*)(Wlin + (size_t)c * 512);
  float s = 0.f;
  for (int j = 0; j < 64; ++j) {
    f32x4 a = hf[j], ww = wl[j];
    s += a[0] * ww[0] + a[1] * ww[1] + a[2] * ww[2] + a[3] * ww[3];
  }
  for (int j = 0; j < 64; ++j) {
    f32x4 a = hbk[j], ww = wl[64 + j];
    s += a[0] * ww[0] + a[1] * ww[1] + a[2] * ww[2] + a[3] * ww[3];
  }
  out[tid] = s * (1.0f / 1024.0f) + blin[c];
}

// ---------------- launch -----------------------------------------------------
extern "C" void kernel_launch(void* const* d_in, const int* in_sizes, int n_in,
                              void* d_out, int out_size, void* d_ws, size_t ws_size,
                              hipStream_t stream) {
  const float* emb = (const float*)d_in[0];
  const float* mask = (const float*)d_in[1];
  const float* Wih_f = (const float*)d_in[2];
  const float* Whh_f = (const float*)d_in[3];
  const float* b_f = (const float*)d_in[4];
  const float* Wih_b = (const float*)d_in[5];
  const float* Whh_b = (const float*)d_in[6];
  const float* b_b = (const float*)d_in[7];
  const float* Wlin = (const float*)d_in[8];
  const float* blin = (const float*)d_in[9];
  float* out = (float*)d_out;

  const size_t HBUF_BYTES = (size_t)16 * 2 * 16 * 128 * 8;  // 512 KiB
  const size_t HSUM_BYTES = (size_t)2 * B_ * H_ * 4;        // 256 KiB
  const size_t IMG_BYTES = (size_t)8 * 1024 * 512 * 16;     // 64 MiB
  if (ws_size < HBUF_BYTES + HSUM_BYTES) return;
  const bool prep = ws_size >= HBUF_BYTES + HSUM_BYTES + IMG_BYTES;

  char* ws = (char*)d_ws;
  unsigned long long* Hbuf = (unsigned long long*)ws;
  float* hsum = (float*)(ws + HBUF_BYTES);
  unsigned short* img = (unsigned short*)(ws + HBUF_BYTES + HSUM_BYTES);

  (void)hipMemsetAsync(Hbuf, 0, HBUF_BYTES, stream);  // tags start at 1; replay-safe
  if (prep) {
    prep_kernel<<<16384, 256, 0, stream>>>(emb, mask, img);
    rec_kernel<true><<<32, 512, 0, stream>>>(emb, mask, img, Wih_f, Whh_f, b_f,
                                             Wih_b, Whh_b, b_b, Hbuf, hsum);
  } else {
    rec_kernel<false><<<32, 512, 0, stream>>>(emb, mask, img, Wih_f, Whh_f, b_f,
                                              Wih_b, Whh_b, b_b, Hbuf, hsum);
  }
  head_kernel<<<1, 256, 0, stream>>>(hsum, Wlin, blin, out);
}

// Round 11
// 2020.334 us; speedup vs baseline: 4.4531x; 4.4531x over previous
//
#include <hip/hip_runtime.h>

// LSTMFromEmbeddings: B=128, T=1024, E=256, H=256, C=2, bidirectional + meanpool + linear.
//
// R11 = R8's proven 4-member structure (register-safe: 128 weight VGPRs) + gate-quad
// DPP transpose (no gates LDS round-trip) + parity-double-buffered HS (drops the
// read/write hazard barrier -> ONE lgkm-only barrier per step).
//  rec: 64 persistent wgs = 16 groups (2 dir x 8 batch-blocks of 16) x 4 members
//       (64 units each). Col mapping col' = (2w+i)*16 + 4*qd + qg, unit = qd*16+2w+i,
//       gate = qg. After MFMA, a 4x4 DPP quad transpose gives each lane the 4 gates
//       of (batch 4*l4+qg, units qd*16+2w+{0,1}) -> ew in registers -> publish 1
//       tagged word + own-HS ds_write_b32 -> xg MFMA -> poll peers (skip own member)
//       -> peer-HS int4 write -> barrier.
//  prep: bf16(x*mask) image in LDS-tile layout (gload_lds staging, 2 steps ahead).
//  head: out = (hsum/1024) @ W_lin^T + b_lin.

#define B_ 128
#define T_ 1024
#define E_ 256
#define H_ 256

typedef short short8 __attribute__((ext_vector_type(8)));
typedef float f32x4 __attribute__((ext_vector_type(4)));
typedef float f32x2 __attribute__((ext_vector_type(2)));

__device__ __forceinline__ unsigned short f2bf(float f) {
  unsigned u = __builtin_bit_cast(unsigned, f);
  u += 0x7fffu + ((u >> 16) & 1u);  // RNE
  return (unsigned short)(u >> 16);
}
__device__ __forceinline__ f32x4 mfma16(short8 a, short8 b, f32x4 c) {
  return __builtin_amdgcn_mfma_f32_16x16x32_bf16(a, b, c, 0, 0, 0);
}
__device__ __forceinline__ float rcpf(float x) { return __builtin_amdgcn_rcpf(x); }

// proven R8 elementwise: 5 exp + 3 rcp per unit
__device__ __forceinline__ float lstm_ew(float gi, float gf, float gg, float go, float& c) {
  float ei = __expf(-gi), ef = __expf(-gf), eg = __expf(-2.f * gg);
  float di = 1.f + ei, df = 1.f + ef, dg = 1.f + eg;
  float r1 = rcpf(di * dg);
  float si = r1 * dg;
  float tg = 2.f * (r1 * di) - 1.f;
  c = rcpf(df) * c + si * tg;
  float eo = __expf(-go), ec = __expf(2.f * c);
  float do_ = 1.f + eo, dc = 1.f + ec;
  float r3 = rcpf(do_ * dc);
  float so = r3 * dc;
  float th = 1.f - 2.f * (r3 * do_);
  return so * th;
}

__device__ __forceinline__ short8 cvt8(f32x4 v0, f32x4 v1) {
  short8 o;
  o[0] = (short)f2bf(v0[0]); o[1] = (short)f2bf(v0[1]);
  o[2] = (short)f2bf(v0[2]); o[3] = (short)f2bf(v0[3]);
  o[4] = (short)f2bf(v1[0]); o[5] = (short)f2bf(v1[1]);
  o[6] = (short)f2bf(v1[2]); o[7] = (short)f2bf(v1[3]);
  return o;
}

__device__ __forceinline__ void bar_lds() {  // LDS-only barrier; vmem stays in flight
  asm volatile("s_waitcnt lgkmcnt(0)" ::: "memory");
  __builtin_amdgcn_s_barrier();
}

__device__ __forceinline__ void gload16(const void* g, void* l) {
  __builtin_amdgcn_global_load_lds(
      (const __attribute__((address_space(1))) void*)g,
      (__attribute__((address_space(3))) void*)l, 16, 0, 0);
}

template <int CTRL>
__device__ __forceinline__ float dppf(float v) {
  int x = __builtin_bit_cast(int, v);
  x = __builtin_amdgcn_update_dpp(0, x, CTRL, 0xF, 0xF, true);
  return __builtin_bit_cast(float, x);
}
#define DPP_X1 0xB1  // quad_perm [1,0,3,2]
#define DPP_X2 0x4E  // quad_perm [2,3,0,1]

// ---------------- prep: x image in LDS-tile layout ---------------------------
__global__ __launch_bounds__(256, 4) void prep_kernel(
    const float* __restrict__ x, const float* __restrict__ mask,
    unsigned short* __restrict__ img) {
  int gid = blockIdx.x * 256 + threadIdx.x;
  int i = gid & 511;
  int tt = (gid >> 9) & 1023;
  int bblk = gid >> 19;
  int r = i >> 5, s = i & 31, kc = s ^ (r & 7);
  int b = bblk * 16 + r;
  const f32x4* src = (const f32x4*)(x + ((size_t)b * T_ + tt) * E_ + kc * 8);
  float mk = mask[(size_t)b * T_ + tt];
  ((short8*)img)[gid] = cvt8(src[0] * mk, src[1] * mk);
}

// ---------------- rec: fused projection + recurrence --------------------------
// grid 64, 512 threads. g = bid & 15, m = bid >> 4 (members co-XCD heuristic).
// Member m owns units [m*64, m*64+64).
template <bool PREP>
__global__ __launch_bounds__(512, 1) void rec_kernel(
    const float* __restrict__ x, const float* __restrict__ mask,
    const unsigned short* __restrict__ img,
    const float* __restrict__ WihF, const float* __restrict__ WhhF,
    const float* __restrict__ bF, const float* __restrict__ WihB,
    const float* __restrict__ WhhB, const float* __restrict__ bB,
    unsigned long long* __restrict__ Hbuf, float* __restrict__ hsum) {
  __shared__ __align__(16) short XS[2][16 * 256];  // x stage, parity dbuf (16KB)
  __shared__ __align__(16) short HS[2][16 * 256];  // h stage, parity dbuf (16KB)

  const int bid = blockIdx.x;
  const int g = bid & 15, m = bid >> 4;
  const int d = g >> 3, bblk = g & 7;
  const int tid = threadIdx.x;
  const int w = tid >> 6, l = tid & 63, l15 = l & 15, l4 = l >> 4;
  const int qd = l15 >> 2, qg = l15 & 3;
  const int sr = tid >> 5, sc = tid & 31;
  const int b_local = l4 * 4 + qg;  // post-transpose batch of this lane
  const int gb_s = bblk * 16 + sr;  // fallback staging batch

  const float* Wih = d ? WihB : WihF;
  const float* Whh = d ? WhhB : WhhF;
  const float* bias = d ? bB : bF;

  // ---- weight fragments -> registers ----
  // col' = (2w+i)*16 + 4*qd + qg  ->  unit u_local = qd*16 + 2w + i, gate = qg.
  short8 wi[2][8], wh[2][8];
  float biasv[2];
#pragma unroll
  for (int i = 0; i < 2; ++i) {
    int ul = qd * 16 + 2 * w + i;
    size_t nat = (size_t)(qg * 256 + m * 64 + ul);
    biasv[i] = bias[nat];
#pragma unroll
    for (int kb = 0; kb < 8; ++kb) {
      const f32x4* pi = (const f32x4*)(Wih + nat * E_ + kb * 32 + l4 * 8);
      wi[i][kb] = cvt8(pi[0], pi[1]);
      const f32x4* ph = (const f32x4*)(Whh + nat * H_ + kb * 32 + l4 * 8);
      wh[i][kb] = cvt8(ph[0], ph[1]);
    }
  }

  // x image source pointer; one 8KB tile per t
  const int dstep = d ? -8192 : 8192;
  const char* gsrc = (const char*)img +
      ((size_t)(bblk * 1024 + (d ? (T_ - 1) : 0)) * 8192) + (size_t)tid * 16;

  // ---- prologue: HS[0]=0; stage x_0 (and x_1 for PREP); acc = bias + xg_0 ----
  ((int4*)HS)[tid] = (int4){0, 0, 0, 0};  // zeros HS[0] (8KB)
  if constexpr (PREP) {
    gload16(gsrc, (char*)XS[0] + w * 1024);
    gload16(gsrc + dstep, (char*)XS[1] + w * 1024);
    gsrc += 2 * dstep;
  } else {
    int ts = d ? (T_ - 1) : 0;
    const f32x4* px = (const f32x4*)(x + ((size_t)gb_s * T_ + ts) * E_ + sc * 8);
    float mk = mask[(size_t)gb_s * T_ + ts];
    ((short8*)XS[0])[sr * 32 + (sc ^ (sr & 7))] = cvt8(px[0] * mk, px[1] * mk);
  }
  __syncthreads();  // drains gloads + HS[0] zeros visible

  f32x4 acc[2], accB[2];
  acc[0] = (f32x4){biasv[0], biasv[0], biasv[0], biasv[0]};
  acc[1] = (f32x4){biasv[1], biasv[1], biasv[1], biasv[1]};
  accB[0] = (f32x4){0.f, 0.f, 0.f, 0.f};
  accB[1] = (f32x4){0.f, 0.f, 0.f, 0.f};
#pragma unroll
  for (int kp = 0; kp < 4; ++kp) {
    short8 a0 = ((short8*)XS[0])[l15 * 32 + ((kp * 8 + l4) ^ (l15 & 7))];
    short8 a1 = ((short8*)XS[0])[l15 * 32 + ((kp * 8 + 4 + l4) ^ (l15 & 7))];
    acc[0] = mfma16(a0, wi[0][2 * kp], acc[0]);
    acc[1] = mfma16(a0, wi[1][2 * kp], acc[1]);
    accB[0] = mfma16(a1, wi[0][2 * kp + 1], accB[0]);
    accB[1] = mfma16(a1, wi[1][2 * kp + 1], accB[1]);
  }
  __syncthreads();  // XS[0] consumed before first in-loop gload overwrites it

  const bool s1 = (l & 1) != 0;
  const bool s2 = (l & 2) != 0;
  float cs[2] = {0.f, 0.f};
  float hsums[2] = {0.f, 0.f};

  for (int t = 0; t < T_; ++t) {
    const bool more = (t + 1 < T_);

    if constexpr (PREP) {
      if (t + 2 < T_) {  // stage x_{t+2}; retired by this step's poll vmcnt + barrier
        gload16(gsrc, (char*)XS[t & 1] + w * 1024);
        gsrc += dstep;
      }
    }
    f32x4 xv0, xv1;
    float mk = 0.f;
    if constexpr (!PREP) {
      if (more) {
        int ts = d ? (T_ - 2 - t) : (t + 1);
        const f32x4* px = (const f32x4*)(x + ((size_t)gb_s * T_ + ts) * E_ + sc * 8);
        xv0 = px[0]; xv1 = px[1];
        mk = mask[(size_t)gb_s * T_ + ts];
      }
    }

    // hh product into acc (acc holds bias + xg_t); HS[t&1] holds h_t
    {
      const short8* hsP = (const short8*)HS[t & 1];
#pragma unroll
      for (int kp = 0; kp < 4; ++kp) {
        short8 a0 = hsP[l15 * 32 + ((kp * 8 + l4) ^ (l15 & 7))];
        short8 a1 = hsP[l15 * 32 + ((kp * 8 + 4 + l4) ^ (l15 & 7))];
        acc[0] = mfma16(a0, wh[0][2 * kp], acc[0]);
        acc[1] = mfma16(a0, wh[1][2 * kp], acc[1]);
        accB[0] = mfma16(a1, wh[0][2 * kp + 1], accB[0]);
        accB[1] = mfma16(a1, wh[1][2 * kp + 1], accB[1]);
      }
    }

    // 4x4 DPP quad transpose + ew. Before: lane(col c = 4qd+qg) holds rows 0..3.
    // After: lane(qg) holds gates 0..3 of batch 4*l4+qg for unit qd*16+2w+i.
    float h[2];
#pragma unroll
    for (int i = 0; i < 2; ++i) {
      float a = acc[i][0] + accB[i][0];
      float b1 = acc[i][1] + accB[i][1];
      float c = acc[i][2] + accB[i][2];
      float dd = acc[i][3] + accB[i][3];
      float ap = dppf<DPP_X1>(a), bp = dppf<DPP_X1>(b1);
      float cp = dppf<DPP_X1>(c), dp = dppf<DPP_X1>(dd);
      float z0 = s1 ? bp : a, z1 = s1 ? b1 : ap;
      float z2 = s1 ? dp : c, z3 = s1 ? dd : cp;
      float z0p = dppf<DPP_X2>(z0), z1p = dppf<DPP_X2>(z1);
      float z2p = dppf<DPP_X2>(z2), z3p = dppf<DPP_X2>(z3);
      float t0 = s2 ? z2p : z0, t1 = s2 ? z3p : z1;
      float t2 = s2 ? z2 : z0p, t3 = s2 ? z3 : z1p;
      h[i] = lstm_ew(t0, t1, t2, t3, cs[i]);
      hsums[i] += h[i];
    }

    if (more) {
      const unsigned tag = (unsigned)(t + 1);
      const size_t base = ((size_t)g * 2 + (tag & 1)) * 16;  // [grp][parity][16b][128w]

      // publish: 1 tagged word for units (gu, gu+1), gu = m*64 + qd*16 + 2w
      unsigned pay;
      asm("v_cvt_pk_bf16_f32 %0, %1, %2" : "=v"(pay) : "v"(h[0]), "v"(h[1]));
      unsigned long long word = (((unsigned long long)tag) << 32) | (unsigned long long)pay;
      __hip_atomic_store(&Hbuf[(base + b_local) * 128 + m * 32 + qd * 8 + w], word,
                         __ATOMIC_RELAXED, __HIP_MEMORY_SCOPE_AGENT);
      asm volatile("" ::: "memory");  // publish before polls

      // own HS slice: 2 units -> one b32 write into HS[(t+1)&1]
      {
        int cg = m * 8 + 2 * qd + (w >> 2);  // chunk of gu
        *(int*)((char*)HS[(t + 1) & 1] +
                (size_t)(b_local * 32 + (cg ^ (b_local & 7))) * 16 + 4 * (w & 3)) = (int)pay;
      }

      if constexpr (!PREP) {
        ((short8*)XS[(t + 1) & 1])[sr * 32 + (sc ^ (sr & 7))] = cvt8(xv0 * mk, xv1 * mk);
        bar_lds();
      }

      // acc = bias + xg_{t+1} (fills publish->visibility window)
      acc[0] = (f32x4){biasv[0], biasv[0], biasv[0], biasv[0]};
      acc[1] = (f32x4){biasv[1], biasv[1], biasv[1], biasv[1]};
      accB[0] = (f32x4){0.f, 0.f, 0.f, 0.f};
      accB[1] = (f32x4){0.f, 0.f, 0.f, 0.f};
      const short8* xsN = (const short8*)XS[(t + 1) & 1];
#pragma unroll
      for (int kp = 0; kp < 4; ++kp) {
        short8 a0 = xsN[l15 * 32 + ((kp * 8 + l4) ^ (l15 & 7))];
        short8 a1 = xsN[l15 * 32 + ((kp * 8 + 4 + l4) ^ (l15 & 7))];
        acc[0] = mfma16(a0, wi[0][2 * kp], acc[0]);
        acc[1] = mfma16(a0, wi[1][2 * kp], acc[1]);
        accB[0] = mfma16(a1, wi[0][2 * kp + 1], accB[0]);
        accB[1] = mfma16(a1, wi[1][2 * kp + 1], accB[1]);
      }

      // poll peers' words (skip own member's chunk — written lane-direct above)
      int pc = sc >> 3;  // member owning words 4sc..4sc+3
      if (pc != m) {
        const unsigned long long* rp = &Hbuf[(base + sr) * 128 + sc * 4];
        unsigned long long vv[4];
#pragma unroll
        for (int j = 0; j < 4; ++j)
          vv[j] = __hip_atomic_load(&rp[j], __ATOMIC_RELAXED, __HIP_MEMORY_SCOPE_AGENT);
        asm volatile("" ::: "memory");
        for (;;) {  // batched parallel retry rounds
          bool ok = true;
#pragma unroll
          for (int j = 0; j < 4; ++j) ok &= ((unsigned)(vv[j] >> 32) == tag);
          if (ok) break;
#pragma unroll
          for (int j = 0; j < 4; ++j)
            if ((unsigned)(vv[j] >> 32) != tag)
              vv[j] = __hip_atomic_load(&rp[j], __ATOMIC_RELAXED, __HIP_MEMORY_SCOPE_AGENT);
          asm volatile("" ::: "memory");
        }
        int4 hw;
        hw.x = (int)(unsigned)vv[0]; hw.y = (int)(unsigned)vv[1];
        hw.z = (int)(unsigned)vv[2]; hw.w = (int)(unsigned)vv[3];
        *(int4*)((char*)HS[(t + 1) & 1] + (size_t)(sr * 32 + (sc ^ (sr & 7))) * 16) = hw;
      }
      bar_lds();  // HS[(t+1)&1] (own+peer) visible; XS[(t+1)&1] fully read
    }
  }

  // pooled sums: lane owns (b = bblk*16 + b_local, units gu, gu+1) — 8B store
  {
    int gb_t = bblk * 16 + b_local;
    int gu = m * 64 + qd * 16 + 2 * w;
    f32x2 hv = {hsums[0], hsums[1]};
    *(f32x2*)(hsum + ((size_t)d * B_ + gb_t) * H_ + gu) = hv;
  }
}

// ---------------- head: linear ----------------------------------------------
__global__ __launch_bounds__(256, 1) void head_kernel(
    const float* __restrict__ hsum, const float* __restrict__ Wlin,
    const float* __restrict__ blin, float* __restrict__ out) {
  int tid = threadIdx.x;  // 256 = 128 b x 2 c
  int b = tid >> 1, c = tid & 1;
  const f32x4* hf = (const f32x4*)(hsum + (size_t)b * H_);
  const f32x4* hbk = (const f32x4*)(hsum + (size_t)B_ * H_ + (size_t)b * H_);
  const f32x4* wl = (const f32x4*)(Wlin + (size_t)c * 512);
  float s = 0.f;
  for (int j = 0; j < 64; ++j) {
    f32x4 a = hf[j], ww = wl[j];
    s += a[0] * ww[0] + a[1] * ww[1] + a[2] * ww[2] + a[3] * ww[3];
  }
  for (int j = 0; j < 64; ++j) {
    f32x4 a = hbk[j], ww = wl[64 + j];
    s += a[0] * ww[0] + a[1] * ww[1] + a[2] * ww[2] + a[3] * ww[3];
  }
  out[tid] = s * (1.0f / 1024.0f) + blin[c];
}

// ---------------- launch -----------------------------------------------------
extern "C" void kernel_launch(void* const* d_in, const int* in_sizes, int n_in,
                              void* d_out, int out_size, void* d_ws, size_t ws_size,
                              hipStream_t stream) {
  const float* emb = (const float*)d_in[0];
  const float* mask = (const float*)d_in[1];
  const float* Wih_f = (const float*)d_in[2];
  const float* Whh_f = (const float*)d_in[3];
  const float* b_f = (const float*)d_in[4];
  const float* Wih_b = (const float*)d_in[5];
  const float* Whh_b = (const float*)d_in[6];
  const float* b_b = (const float*)d_in[7];
  const float* Wlin = (const float*)d_in[8];
  const float* blin = (const float*)d_in[9];
  float* out = (float*)d_out;

  const size_t HBUF_BYTES = (size_t)16 * 2 * 16 * 128 * 8;  // 512 KiB
  const size_t HSUM_BYTES = (size_t)2 * B_ * H_ * 4;        // 256 KiB
  const size_t IMG_BYTES = (size_t)8 * 1024 * 512 * 16;     // 64 MiB
  if (ws_size < HBUF_BYTES + HSUM_BYTES) return;
  const bool prep = ws_size >= HBUF_BYTES + HSUM_BYTES + IMG_BYTES;

  char* ws = (char*)d_ws;
  unsigned long long* Hbuf = (unsigned long long*)ws;
  float* hsum = (float*)(ws + HBUF_BYTES);
  unsigned short* img = (unsigned short*)(ws + HBUF_BYTES + HSUM_BYTES);

  (void)hipMemsetAsync(Hbuf, 0, HBUF_BYTES, stream);  // tags start at 1; replay-safe
  if (prep) {
    prep_kernel<<<16384, 256, 0, stream>>>(emb, mask, img);
    rec_kernel<true><<<64, 512, 0, stream>>>(emb, mask, img, Wih_f, Whh_f, b_f,
                                             Wih_b, Whh_b, b_b, Hbuf, hsum);
  } else {
    rec_kernel<false><<<64, 512, 0, stream>>>(emb, mask, img, Wih_f, Whh_f, b_f,
                                              Wih_b, Whh_b, b_b, Hbuf, hsum);
  }
  head_kernel<<<1, 256, 0, stream>>>(hsum, Wlin, blin, out);
}